// Round 3
// baseline (355.227 us; speedup 1.0000x reference)
//
#include <hip/hip_runtime.h>
#include <hip/hip_bf16.h>
#include <cstdint>
#include <cstddef>

#define EMBED 1280
#define NHEAD 16
#define HD 80
#define ROT 40
#define SEQL 2048
#define QKV_N 3840
#define QKV_STRIDE (NHEAD * SEQL * HD)   // elems per Q/K/V buffer = 2,621,440

typedef __attribute__((ext_vector_type(8))) short short8v;  // 8 bf16 (4 VGPRs)
typedef __attribute__((ext_vector_type(4))) float f32x4;    // MFMA accumulator

__device__ inline unsigned short f2bf(float f) {            // RNE float->bf16
    unsigned u = __float_as_uint(f);
    u += 0x7FFFu + ((u >> 16) & 1u);
    return (unsigned short)(u >> 16);
}
__device__ inline float bf2f(unsigned short h) {
    return __uint_as_float(((unsigned)h) << 16);
}

// ---------------------------------------------------------------------------
// bf16x3 split MFMA GEMM: C[m][n] = sum_k A[m][k]*B[n][k] + bias[n]
// A:[M][K], B:[N][K] row-major fp32. Split each operand into hi+lo bf16,
// accumulate hi*hi + hi*lo + lo*hi in fp32 MFMA (error ~1e-5 rel vs fp32).
// Block 256 thr = 4 waves (2x2), tile 128x128, BK=32, mfma_f32_16x16x32_bf16.
// MODE 0: store C row-major [M][N].  MODE 1: scatter into Q/K/V buffers.
// ---------------------------------------------------------------------------
template <int MODE>
__global__ __launch_bounds__(256) void gemm_mfma_kernel(
    const float* __restrict__ A, const float* __restrict__ B,
    const float* __restrict__ bias, float* __restrict__ C,
    int M, int N, int K)
{
    // [plane][row][k] bf16, 64B rows; 16B blocks XOR-swizzled by (row&3)
    __shared__ unsigned short As[2 * 128 * 32];   // 16 KB
    __shared__ unsigned short Bs[2 * 128 * 32];   // 16 KB

    const int tid  = threadIdx.x;
    const int m0   = blockIdx.y * 128;
    const int n0   = blockIdx.x * 128;
    const int wave = tid >> 6;
    const int lane = tid & 63;
    const int wm   = (wave >> 1) * 64;
    const int wn   = (wave & 1) * 64;
    const int lrow = lane & 15;
    const int lg   = lane >> 4;          // k-group 0..3

    f32x4 acc[4][4];
#pragma unroll
    for (int i = 0; i < 4; ++i)
#pragma unroll
        for (int j = 0; j < 4; ++j) acc[i][j] = (f32x4){0.f, 0.f, 0.f, 0.f};

    for (int k0 = 0; k0 < K; k0 += 32) {
        // ---- issue global loads early (latency hides under prior MFMA phase)
        float4 ar[4], br[4];
#pragma unroll
        for (int l = 0; l < 4; ++l) {
            int id = l * 256 + tid;          // 0..1023 = 128 rows x 8 float4
            int r = id >> 3, c = id & 7;
            ar[l] = *reinterpret_cast<const float4*>(&A[(size_t)(m0 + r) * K + k0 + c * 4]);
            br[l] = *reinterpret_cast<const float4*>(&B[(size_t)(n0 + r) * K + k0 + c * 4]);
        }
        __syncthreads();   // prior tile's reads complete
        // ---- convert + swizzled LDS write (hi plane, lo plane)
#pragma unroll
        for (int l = 0; l < 4; ++l) {
            int id = l * 256 + tid;
            int r = id >> 3, c = id & 7;
            int base = r * 32 + (((c >> 1) ^ (r & 3)) << 3) + ((c & 1) << 2);
            float4 v = ar[l];
            unsigned short h0 = f2bf(v.x), h1 = f2bf(v.y), h2 = f2bf(v.z), h3 = f2bf(v.w);
            unsigned short g0 = f2bf(v.x - bf2f(h0)), g1 = f2bf(v.y - bf2f(h1));
            unsigned short g2 = f2bf(v.z - bf2f(h2)), g3 = f2bf(v.w - bf2f(h3));
            uint2 w;
            w.x = (unsigned)h0 | ((unsigned)h1 << 16); w.y = (unsigned)h2 | ((unsigned)h3 << 16);
            *reinterpret_cast<uint2*>(&As[base]) = w;
            w.x = (unsigned)g0 | ((unsigned)g1 << 16); w.y = (unsigned)g2 | ((unsigned)g3 << 16);
            *reinterpret_cast<uint2*>(&As[4096 + base]) = w;
            v = br[l];
            h0 = f2bf(v.x); h1 = f2bf(v.y); h2 = f2bf(v.z); h3 = f2bf(v.w);
            g0 = f2bf(v.x - bf2f(h0)); g1 = f2bf(v.y - bf2f(h1));
            g2 = f2bf(v.z - bf2f(h2)); g3 = f2bf(v.w - bf2f(h3));
            w.x = (unsigned)h0 | ((unsigned)h1 << 16); w.y = (unsigned)h2 | ((unsigned)h3 << 16);
            *reinterpret_cast<uint2*>(&Bs[base]) = w;
            w.x = (unsigned)g0 | ((unsigned)g1 << 16); w.y = (unsigned)g2 | ((unsigned)g3 << 16);
            *reinterpret_cast<uint2*>(&Bs[4096 + base]) = w;
        }
        __syncthreads();
        // ---- fragment reads + MFMA (hi*hi + hi*lo + lo*hi)
        short8v bh[4], bl[4];
#pragma unroll
        for (int fn = 0; fn < 4; ++fn) {
            int row = wn + fn * 16 + lrow;
            int idx = row * 32 + ((lg ^ (row & 3)) << 3);
            bh[fn] = *reinterpret_cast<const short8v*>(&Bs[idx]);
            bl[fn] = *reinterpret_cast<const short8v*>(&Bs[4096 + idx]);
        }
#pragma unroll
        for (int fm = 0; fm < 4; ++fm) {
            int row = wm + fm * 16 + lrow;
            int idx = row * 32 + ((lg ^ (row & 3)) << 3);
            short8v ah = *reinterpret_cast<const short8v*>(&As[idx]);
            short8v al = *reinterpret_cast<const short8v*>(&As[4096 + idx]);
#pragma unroll
            for (int fn = 0; fn < 4; ++fn) {
                acc[fm][fn] = __builtin_amdgcn_mfma_f32_16x16x32_bf16(ah, bh[fn], acc[fm][fn], 0, 0, 0);
                acc[fm][fn] = __builtin_amdgcn_mfma_f32_16x16x32_bf16(ah, bl[fn], acc[fm][fn], 0, 0, 0);
                acc[fm][fn] = __builtin_amdgcn_mfma_f32_16x16x32_bf16(al, bh[fn], acc[fm][fn], 0, 0, 0);
            }
        }
    }

    // ---- epilogue: C/D layout col=lane&15, row=(lane>>4)*4+reg [m89/m91]
#pragma unroll
    for (int fn = 0; fn < 4; ++fn) {
        int n = n0 + wn + fn * 16 + lrow;
        float bcol = bias[n];
        if (MODE == 0) {
#pragma unroll
            for (int fm = 0; fm < 4; ++fm) {
#pragma unroll
                for (int q = 0; q < 4; ++q) {
                    int m = m0 + wm + fm * 16 + lg * 4 + q;
                    C[(size_t)m * N + n] = acc[fm][fn][q] + bcol;
                }
            }
        } else {
            int part = n / EMBED;
            int rem  = n - part * EMBED;
            int head = rem / HD;
            int d    = rem - head * HD;
            float* dst = C + (size_t)part * QKV_STRIDE + (size_t)head * SEQL * HD + d;
#pragma unroll
            for (int fm = 0; fm < 4; ++fm) {
#pragma unroll
                for (int q = 0; q < 4; ++q) {
                    int m = m0 + wm + fm * 16 + lg * 4 + q;
                    dst[(size_t)m * HD] = acc[fm][fn][q] + bcol;
                }
            }
        }
    }
}

// ---------------------------------------------------------------------------
// Rotary (in-place on Q and K, [head][seq][dim] layout)
// ---------------------------------------------------------------------------
__global__ __launch_bounds__(256) void rotary_kernel(
    float* __restrict__ Q, float* __restrict__ K, const float* __restrict__ rpe)
{
    int idx = blockIdx.x * 256 + threadIdx.x;       // 0 .. 2*16*2048*40-1
    int r = idx % ROT;
    int s = (idx / ROT) & (SEQL - 1);
    int h = (idx / (ROT * SEQL)) & (NHEAD - 1);
    float* buf = (idx >= NHEAD * SEQL * ROT) ? K : Q;
    float* p = buf + ((size_t)h * SEQL + s) * HD;
    float ang = rpe[s * ROT + r];
    float c = cosf(ang), sn = sinf(ang);
    float t1 = p[r], t2 = p[r + ROT];
    p[r]       = t1 * c - t2 * sn;
    p[r + ROT] = t2 * c + t1 * sn;
}

// ---------------------------------------------------------------------------
// Flash attention with per-row segment masking (varlen via cu_seqlens).
// Grid: (SEQ/64, NHEAD). Block 256. 64 q-rows per block, 64-key tiles.
// K staged transposed [d][key] for GEMM-style scores; V overlaid in same LDS.
// ---------------------------------------------------------------------------
__global__ __launch_bounds__(256) void attn_kernel(
    const float* __restrict__ Qb, const float* __restrict__ Kb,
    const float* __restrict__ Vb, const int* __restrict__ cu, int nseg,
    float* __restrict__ ctx)
{
    __shared__ float q_s[HD][68];        // [80][68] transposed Q tile
    __shared__ float kv_s[HD * 68];      // K: [80][68] transposed | V: [64][84] row-major
    __shared__ float s_lds[64][68];      // scores, then probabilities

    const int tid = threadIdx.x;
    const int h   = blockIdx.y;
    const int r   = tid >> 2;            // row in chunk, 0..63
    const int ql  = tid & 3;             // dim-group / key-group lane
    const int r0  = blockIdx.x * 64;
    const int row = r0 + r;

    // per-row segment bounds + block-wide key range
    int start = cu[nseg], end = SEQL;
    int blo = cu[nseg], bhi = SEQL;
    const int r1 = r0 + 63;
    for (int i = 0; i < nseg; ++i) {
        int a = cu[i], b = cu[i + 1];
        if (row >= a && row < b) { start = a; end = b; }
        if (r0  >= a && r0  < b) blo = a;
        if (r1  >= a && r1  < b) bhi = b;
    }

    // load Q tile transposed: q_s[d][row]
    const float* Qh = Qb + ((size_t)h * SEQL + r0) * HD;
#pragma unroll
    for (int l = 0; l < 5; ++l) {
        int idx = tid + l * 256;            // 0..1279
        int rr = idx / 20;
        int cc = (idx % 20) * 4;
        float4 t = *reinterpret_cast<const float4*>(&Qh[rr * HD + cc]);
        q_s[cc + 0][rr] = t.x; q_s[cc + 1][rr] = t.y;
        q_s[cc + 2][rr] = t.z; q_s[cc + 3][rr] = t.w;
    }

    float m = -1e30f, l_sum = 0.f;
    float o[20];
#pragma unroll
    for (int t = 0; t < 20; ++t) o[t] = 0.f;

    const float scale = 0.11180339887498949f;   // 1/sqrt(80)
    const int tm2 = tid >> 4, tn2 = tid & 15;
    const float* Kh = Kb + (size_t)h * SEQL * HD;
    const float* Vh = Vb + (size_t)h * SEQL * HD;

    __syncthreads();

    for (int kb = (blo & ~63); kb < bhi; kb += 64) {
        // ---- stage K tile transposed: kv_s[d*68 + j]
#pragma unroll
        for (int l = 0; l < 5; ++l) {
            int idx = tid + l * 256;
            int j = idx / 20;
            int cc = (idx % 20) * 4;
            int key = kb + j; if (key >= SEQL) key = SEQL - 1;
            float4 t = *reinterpret_cast<const float4*>(&Kh[(size_t)key * HD + cc]);
            kv_s[(cc + 0) * 68 + j] = t.x; kv_s[(cc + 1) * 68 + j] = t.y;
            kv_s[(cc + 2) * 68 + j] = t.z; kv_s[(cc + 3) * 68 + j] = t.w;
        }
        __syncthreads();

        // ---- scores: 64x64 GEMM, thread computes 4 rows x 4 keys
        {
            float sc[4][4];
#pragma unroll
            for (int i = 0; i < 4; ++i)
#pragma unroll
                for (int j = 0; j < 4; ++j) sc[i][j] = 0.f;
#pragma unroll 4
            for (int d = 0; d < HD; ++d) {
                float4 qa = *reinterpret_cast<const float4*>(&q_s[d][tm2 * 4]);
                float4 ka = *reinterpret_cast<const float4*>(&kv_s[d * 68 + tn2 * 4]);
                float qv[4] = {qa.x, qa.y, qa.z, qa.w};
                float kv[4] = {ka.x, ka.y, ka.z, ka.w};
#pragma unroll
                for (int i = 0; i < 4; ++i)
#pragma unroll
                    for (int j = 0; j < 4; ++j)
                        sc[i][j] = fmaf(qv[i], kv[j], sc[i][j]);
            }
#pragma unroll
            for (int i = 0; i < 4; ++i)
#pragma unroll
                for (int j = 0; j < 4; ++j)
                    s_lds[tm2 * 4 + i][tn2 * 4 + j] = sc[i][j] * scale;
        }
        __syncthreads();

        // ---- stage V tile row-major into same LDS: kv_s[j*84 + d]
#pragma unroll
        for (int l = 0; l < 5; ++l) {
            int idx = tid + l * 256;
            int j = idx / 20;
            int cc = (idx % 20) * 4;
            int key = kb + j; if (key >= SEQL) key = SEQL - 1;
            *reinterpret_cast<float4*>(&kv_s[j * 84 + cc]) =
                *reinterpret_cast<const float4*>(&Vh[(size_t)key * HD + cc]);
        }

        // ---- online softmax partial (each thread owns 16 keys of its row)
        {
            int jlo = start - kb; if (jlo < 0) jlo = 0;
            int jhi = end - kb;   if (jhi > 64) jhi = 64;
            float sv[16];
            float tmax = -1e30f;
#pragma unroll
            for (int jj = 0; jj < 16; ++jj) {
                int j = ql * 16 + jj;
                float s = s_lds[r][j];
                bool valid = (j >= jlo) && (j < jhi);
                s = valid ? s : -1e30f;
                sv[jj] = s;
                tmax = fmaxf(tmax, s);
            }
            tmax = fmaxf(tmax, __shfl_xor(tmax, 1));
            tmax = fmaxf(tmax, __shfl_xor(tmax, 2));
            float m_new = fmaxf(m, tmax);
            float alpha = expf(m - m_new);
            float psum = 0.f;
#pragma unroll
            for (int jj = 0; jj < 16; ++jj) {
                int j = ql * 16 + jj;
                float p = (sv[jj] > -1e29f) ? expf(sv[jj] - m_new) : 0.f;
                s_lds[r][j] = p;
                psum += p;
            }
            psum += __shfl_xor(psum, 1);
            psum += __shfl_xor(psum, 2);
            l_sum = l_sum * alpha + psum;
            m = m_new;
#pragma unroll
            for (int t = 0; t < 20; ++t) o[t] *= alpha;
        }
        __syncthreads();   // V staged + probabilities written

        // ---- PV: thread accumulates 20 dims (ql*20..) of its row
#pragma unroll 2
        for (int j = 0; j < 64; ++j) {
            float p = s_lds[r][j];
            const float* vp = &kv_s[j * 84 + ql * 20];
            float4 v0 = *reinterpret_cast<const float4*>(&vp[0]);
            float4 v1 = *reinterpret_cast<const float4*>(&vp[4]);
            float4 v2 = *reinterpret_cast<const float4*>(&vp[8]);
            float4 v3 = *reinterpret_cast<const float4*>(&vp[12]);
            float4 v4 = *reinterpret_cast<const float4*>(&vp[16]);
            o[0]  = fmaf(p, v0.x, o[0]);  o[1]  = fmaf(p, v0.y, o[1]);
            o[2]  = fmaf(p, v0.z, o[2]);  o[3]  = fmaf(p, v0.w, o[3]);
            o[4]  = fmaf(p, v1.x, o[4]);  o[5]  = fmaf(p, v1.y, o[5]);
            o[6]  = fmaf(p, v1.z, o[6]);  o[7]  = fmaf(p, v1.w, o[7]);
            o[8]  = fmaf(p, v2.x, o[8]);  o[9]  = fmaf(p, v2.y, o[9]);
            o[10] = fmaf(p, v2.z, o[10]); o[11] = fmaf(p, v2.w, o[11]);
            o[12] = fmaf(p, v3.x, o[12]); o[13] = fmaf(p, v3.y, o[13]);
            o[14] = fmaf(p, v3.z, o[14]); o[15] = fmaf(p, v3.w, o[15]);
            o[16] = fmaf(p, v4.x, o[16]); o[17] = fmaf(p, v4.y, o[17]);
            o[18] = fmaf(p, v4.z, o[18]); o[19] = fmaf(p, v4.w, o[19]);
        }
        __syncthreads();   // kv_s free for next K tile
    }

    // epilogue: ctx[row][h*80 + ql*20 .. +19]
    float inv = 1.f / l_sum;
    float* cp = &ctx[(size_t)row * EMBED + h * HD + ql * 20];
#pragma unroll
    for (int t = 0; t < 5; ++t) {
        float4 w;
        w.x = o[t * 4 + 0] * inv; w.y = o[t * 4 + 1] * inv;
        w.z = o[t * 4 + 2] * inv; w.w = o[t * 4 + 3] * inv;
        *reinterpret_cast<float4*>(&cp[t * 4]) = w;
    }
}

// ---------------------------------------------------------------------------
extern "C" void kernel_launch(void* const* d_in, const int* in_sizes, int n_in,
                              void* d_out, int out_size, void* d_ws, size_t ws_size,
                              hipStream_t stream)
{
    const float* x      = (const float*)d_in[0];
    const float* rpe    = (const float*)d_in[1];
    const int*   cu     = (const int*)d_in[2];
    // d_in[3] = max_seqlen (unused)
    const float* qkv_w  = (const float*)d_in[4];
    const float* qkv_b  = (const float*)d_in[5];
    const float* proj_w = (const float*)d_in[6];
    const float* proj_b = (const float*)d_in[7];

    float* ws  = (float*)d_ws;
    float* Q   = ws;
    float* K   = ws + (size_t)QKV_STRIDE;
    float* V   = ws + (size_t)2 * QKV_STRIDE;
    float* ctx = ws + (size_t)3 * QKV_STRIDE;

    const int nseg = in_sizes[2] - 1;

    // 1) QKV projection (bf16x3 MFMA), scattered into Q/K/V [head][seq][dim]
    gemm_mfma_kernel<1><<<dim3(QKV_N / 128, SEQL / 128), 256, 0, stream>>>(
        x, qkv_w, qkv_b, Q, SEQL, QKV_N, EMBED);

    // 2) rotary on Q,K in place
    rotary_kernel<<<(2 * NHEAD * SEQL * ROT) / 256, 256, 0, stream>>>(Q, K, rpe);

    // 3) segmented flash attention -> ctx [seq][1280]
    attn_kernel<<<dim3(SEQL / 64, NHEAD), 256, 0, stream>>>(Q, K, V, cu, nseg, ctx);

    // 4) output projection (bf16x3 MFMA)
    gemm_mfma_kernel<0><<<dim3(EMBED / 128, SEQL / 128), 256, 0, stream>>>(
        ctx, proj_w, proj_b, (float*)d_out, SEQL, EMBED, EMBED);
}

// Round 6
// 287.816 us; speedup vs baseline: 1.2342x; 1.2342x over previous
//
#include <hip/hip_runtime.h>
#include <hip/hip_bf16.h>
#include <cstdint>
#include <cstddef>

#define EMBED 1280
#define NHEAD 16
#define HD 80
#define ROT 40
#define SEQL 2048
#define QKV_N 3840
#define QKV_STRIDE (NHEAD * SEQL * HD)   // elems per Q/K/V buffer = 2,621,440

typedef __attribute__((ext_vector_type(8))) short short8v;  // 8 bf16 (4 VGPRs)
typedef __attribute__((ext_vector_type(4))) short short4v;  // 4 bf16 (8B)
typedef __attribute__((ext_vector_type(4))) float f32x4;    // MFMA accumulator

__device__ inline unsigned short f2bf(float f) {            // RNE float->bf16
    unsigned u = __float_as_uint(f);
    u += 0x7FFFu + ((u >> 16) & 1u);
    return (unsigned short)(u >> 16);
}
__device__ inline float bf2f(unsigned short h) {
    return __uint_as_float(((unsigned)h) << 16);
}

// ---------------------------------------------------------------------------
// Elementwise fp32 -> bf16 hi/lo split (pre-pass for hoisted GEMM staging)
// ---------------------------------------------------------------------------
__global__ __launch_bounds__(256) void split_bf16_kernel(
    const float* __restrict__ src, unsigned short* __restrict__ hi,
    unsigned short* __restrict__ lo, int n4)
{
    int i = blockIdx.x * 256 + threadIdx.x;
    if (i >= n4) return;
    float4 v = reinterpret_cast<const float4*>(src)[i];
    unsigned short h0 = f2bf(v.x), h1 = f2bf(v.y), h2 = f2bf(v.z), h3 = f2bf(v.w);
    short4v hv, lv;
    hv[0] = (short)h0; hv[1] = (short)h1; hv[2] = (short)h2; hv[3] = (short)h3;
    lv[0] = (short)f2bf(v.x - bf2f(h0));
    lv[1] = (short)f2bf(v.y - bf2f(h1));
    lv[2] = (short)f2bf(v.z - bf2f(h2));
    lv[3] = (short)f2bf(v.w - bf2f(h3));
    *reinterpret_cast<short4v*>(&hi[i * 4]) = hv;
    *reinterpret_cast<short4v*>(&lo[i * 4]) = lv;
}

// ---------------------------------------------------------------------------
// bf16x3 split MFMA GEMM, FALLBACK variant (validated round 3, absmax 2e-3):
// converts fp32->bf16 hi/lo inside the staging loop.
// ---------------------------------------------------------------------------
template <int MODE>
__global__ __launch_bounds__(256) void gemm_mfma_kernel(
    const float* __restrict__ A, const float* __restrict__ B,
    const float* __restrict__ bias, float* __restrict__ C,
    int M, int N, int K)
{
    __shared__ unsigned short As[2 * 128 * 32];   // 16 KB
    __shared__ unsigned short Bs[2 * 128 * 32];   // 16 KB

    const int tid  = threadIdx.x;
    const int m0   = blockIdx.y * 128;
    const int n0   = blockIdx.x * 128;
    const int wave = tid >> 6;
    const int lane = tid & 63;
    const int wm   = (wave >> 1) * 64;
    const int wn   = (wave & 1) * 64;
    const int lrow = lane & 15;
    const int lg   = lane >> 4;          // k-group 0..3

    f32x4 acc[4][4];
#pragma unroll
    for (int i = 0; i < 4; ++i)
#pragma unroll
        for (int j = 0; j < 4; ++j) acc[i][j] = (f32x4){0.f, 0.f, 0.f, 0.f};

    for (int k0 = 0; k0 < K; k0 += 32) {
        float4 ar[4], br[4];
#pragma unroll
        for (int l = 0; l < 4; ++l) {
            int id = l * 256 + tid;          // 0..1023 = 128 rows x 8 float4
            int r = id >> 3, c = id & 7;
            ar[l] = *reinterpret_cast<const float4*>(&A[(size_t)(m0 + r) * K + k0 + c * 4]);
            br[l] = *reinterpret_cast<const float4*>(&B[(size_t)(n0 + r) * K + k0 + c * 4]);
        }
        __syncthreads();
#pragma unroll
        for (int l = 0; l < 4; ++l) {
            int id = l * 256 + tid;
            int r = id >> 3, c = id & 7;
            int base = r * 32 + (((c >> 1) ^ (r & 3)) << 3) + ((c & 1) << 2);
            float4 v = ar[l];
            unsigned short h0 = f2bf(v.x), h1 = f2bf(v.y), h2 = f2bf(v.z), h3 = f2bf(v.w);
            unsigned short g0 = f2bf(v.x - bf2f(h0)), g1 = f2bf(v.y - bf2f(h1));
            unsigned short g2 = f2bf(v.z - bf2f(h2)), g3 = f2bf(v.w - bf2f(h3));
            uint2 w;
            w.x = (unsigned)h0 | ((unsigned)h1 << 16); w.y = (unsigned)h2 | ((unsigned)h3 << 16);
            *reinterpret_cast<uint2*>(&As[base]) = w;
            w.x = (unsigned)g0 | ((unsigned)g1 << 16); w.y = (unsigned)g2 | ((unsigned)g3 << 16);
            *reinterpret_cast<uint2*>(&As[4096 + base]) = w;
            v = br[l];
            h0 = f2bf(v.x); h1 = f2bf(v.y); h2 = f2bf(v.z); h3 = f2bf(v.w);
            g0 = f2bf(v.x - bf2f(h0)); g1 = f2bf(v.y - bf2f(h1));
            g2 = f2bf(v.z - bf2f(h2)); g3 = f2bf(v.w - bf2f(h3));
            w.x = (unsigned)h0 | ((unsigned)h1 << 16); w.y = (unsigned)h2 | ((unsigned)h3 << 16);
            *reinterpret_cast<uint2*>(&Bs[base]) = w;
            w.x = (unsigned)g0 | ((unsigned)g1 << 16); w.y = (unsigned)g2 | ((unsigned)g3 << 16);
            *reinterpret_cast<uint2*>(&Bs[4096 + base]) = w;
        }
        __syncthreads();
        short8v bh[4], bl[4];
#pragma unroll
        for (int fn = 0; fn < 4; ++fn) {
            int row = wn + fn * 16 + lrow;
            int idx = row * 32 + ((lg ^ (row & 3)) << 3);
            bh[fn] = *reinterpret_cast<const short8v*>(&Bs[idx]);
            bl[fn] = *reinterpret_cast<const short8v*>(&Bs[4096 + idx]);
        }
#pragma unroll
        for (int fm = 0; fm < 4; ++fm) {
            int row = wm + fm * 16 + lrow;
            int idx = row * 32 + ((lg ^ (row & 3)) << 3);
            short8v ah = *reinterpret_cast<const short8v*>(&As[idx]);
            short8v al = *reinterpret_cast<const short8v*>(&As[4096 + idx]);
#pragma unroll
            for (int fn = 0; fn < 4; ++fn) {
                acc[fm][fn] = __builtin_amdgcn_mfma_f32_16x16x32_bf16(ah, bh[fn], acc[fm][fn], 0, 0, 0);
                acc[fm][fn] = __builtin_amdgcn_mfma_f32_16x16x32_bf16(ah, bl[fn], acc[fm][fn], 0, 0, 0);
                acc[fm][fn] = __builtin_amdgcn_mfma_f32_16x16x32_bf16(al, bh[fn], acc[fm][fn], 0, 0, 0);
            }
        }
    }

#pragma unroll
    for (int fn = 0; fn < 4; ++fn) {
        int n = n0 + wn + fn * 16 + lrow;
        float bcol = bias[n];
        if (MODE == 0) {
#pragma unroll
            for (int fm = 0; fm < 4; ++fm) {
#pragma unroll
                for (int q = 0; q < 4; ++q) {
                    int m = m0 + wm + fm * 16 + lg * 4 + q;
                    C[(size_t)m * N + n] = acc[fm][fn][q] + bcol;
                }
            }
        } else {
            int part = n / EMBED;
            int rem  = n - part * EMBED;
            int head = rem / HD;
            int d    = rem - head * HD;
            float* dst = C + (size_t)part * QKV_STRIDE + (size_t)head * SEQL * HD + d;
#pragma unroll
            for (int fm = 0; fm < 4; ++fm) {
#pragma unroll
                for (int q = 0; q < 4; ++q) {
                    int m = m0 + wm + fm * 16 + lg * 4 + q;
                    dst[(size_t)m * HD] = acc[fm][fn][q] + bcol;
                }
            }
        }
    }
}

// ---------------------------------------------------------------------------
// bf16x3 split MFMA GEMM, HOISTED variant: operands are pre-split bf16 hi/lo
// planes; staging is a pure 16B load -> swizzled LDS copy (no conversion).
// Inner loop / swizzle / epilogue identical to the validated kernel.
// ---------------------------------------------------------------------------
template <int MODE>
__global__ __launch_bounds__(256) void gemm_mfma_pre_kernel(
    const unsigned short* __restrict__ Ah, const unsigned short* __restrict__ Al,
    const unsigned short* __restrict__ Bh, const unsigned short* __restrict__ Bl,
    const float* __restrict__ bias, float* __restrict__ C,
    int M, int N, int K)
{
    __shared__ unsigned short As[2 * 128 * 32];   // 16 KB
    __shared__ unsigned short Bs[2 * 128 * 32];   // 16 KB

    const int tid  = threadIdx.x;
    const int m0   = blockIdx.y * 128;
    const int n0   = blockIdx.x * 128;
    const int wave = tid >> 6;
    const int lane = tid & 63;
    const int wm   = (wave >> 1) * 64;
    const int wn   = (wave & 1) * 64;
    const int lrow = lane & 15;
    const int lg   = lane >> 4;          // k-group 0..3

    f32x4 acc[4][4];
#pragma unroll
    for (int i = 0; i < 4; ++i)
#pragma unroll
        for (int j = 0; j < 4; ++j) acc[i][j] = (f32x4){0.f, 0.f, 0.f, 0.f};

    for (int k0 = 0; k0 < K; k0 += 32) {
        // 128 rows x 4 16B-blocks per plane; 512 assignments / 256 thr = 2 each
        short8v rah[2], ral[2], rbh[2], rbl[2];
#pragma unroll
        for (int l = 0; l < 2; ++l) {
            int id = l * 256 + tid;
            int r = id >> 2, b = id & 3;
            size_t offA = (size_t)(m0 + r) * K + k0 + b * 8;
            size_t offB = (size_t)(n0 + r) * K + k0 + b * 8;
            rah[l] = *reinterpret_cast<const short8v*>(&Ah[offA]);
            ral[l] = *reinterpret_cast<const short8v*>(&Al[offA]);
            rbh[l] = *reinterpret_cast<const short8v*>(&Bh[offB]);
            rbl[l] = *reinterpret_cast<const short8v*>(&Bl[offB]);
        }
        __syncthreads();   // prior tile's fragment reads complete
#pragma unroll
        for (int l = 0; l < 2; ++l) {
            int id = l * 256 + tid;
            int r = id >> 2, b = id & 3;
            int base = r * 32 + ((b ^ (r & 3)) << 3);
            *reinterpret_cast<short8v*>(&As[base]) = rah[l];
            *reinterpret_cast<short8v*>(&As[4096 + base]) = ral[l];
            *reinterpret_cast<short8v*>(&Bs[base]) = rbh[l];
            *reinterpret_cast<short8v*>(&Bs[4096 + base]) = rbl[l];
        }
        __syncthreads();
        short8v bh[4], bl[4];
#pragma unroll
        for (int fn = 0; fn < 4; ++fn) {
            int row = wn + fn * 16 + lrow;
            int idx = row * 32 + ((lg ^ (row & 3)) << 3);
            bh[fn] = *reinterpret_cast<const short8v*>(&Bs[idx]);
            bl[fn] = *reinterpret_cast<const short8v*>(&Bs[4096 + idx]);
        }
#pragma unroll
        for (int fm = 0; fm < 4; ++fm) {
            int row = wm + fm * 16 + lrow;
            int idx = row * 32 + ((lg ^ (row & 3)) << 3);
            short8v ah = *reinterpret_cast<const short8v*>(&As[idx]);
            short8v al = *reinterpret_cast<const short8v*>(&As[4096 + idx]);
#pragma unroll
            for (int fn = 0; fn < 4; ++fn) {
                acc[fm][fn] = __builtin_amdgcn_mfma_f32_16x16x32_bf16(ah, bh[fn], acc[fm][fn], 0, 0, 0);
                acc[fm][fn] = __builtin_amdgcn_mfma_f32_16x16x32_bf16(ah, bl[fn], acc[fm][fn], 0, 0, 0);
                acc[fm][fn] = __builtin_amdgcn_mfma_f32_16x16x32_bf16(al, bh[fn], acc[fm][fn], 0, 0, 0);
            }
        }
    }

#pragma unroll
    for (int fn = 0; fn < 4; ++fn) {
        int n = n0 + wn + fn * 16 + lrow;
        float bcol = bias[n];
        if (MODE == 0) {
#pragma unroll
            for (int fm = 0; fm < 4; ++fm) {
#pragma unroll
                for (int q = 0; q < 4; ++q) {
                    int m = m0 + wm + fm * 16 + lg * 4 + q;
                    C[(size_t)m * N + n] = acc[fm][fn][q] + bcol;
                }
            }
        } else {
            int part = n / EMBED;
            int rem  = n - part * EMBED;
            int head = rem / HD;
            int d    = rem - head * HD;
            float* dst = C + (size_t)part * QKV_STRIDE + (size_t)head * SEQL * HD + d;
#pragma unroll
            for (int fm = 0; fm < 4; ++fm) {
#pragma unroll
                for (int q = 0; q < 4; ++q) {
                    int m = m0 + wm + fm * 16 + lg * 4 + q;
                    dst[(size_t)m * HD] = acc[fm][fn][q] + bcol;
                }
            }
        }
    }
}

// ---------------------------------------------------------------------------
// Rotary (in-place on Q and K, [head][seq][dim] layout) — unchanged
// ---------------------------------------------------------------------------
__global__ __launch_bounds__(256) void rotary_kernel(
    float* __restrict__ Q, float* __restrict__ K, const float* __restrict__ rpe)
{
    int idx = blockIdx.x * 256 + threadIdx.x;
    int r = idx % ROT;
    int s = (idx / ROT) & (SEQL - 1);
    int h = (idx / (ROT * SEQL)) & (NHEAD - 1);
    float* buf = (idx >= NHEAD * SEQL * ROT) ? K : Q;
    float* p = buf + ((size_t)h * SEQL + s) * HD;
    float ang = rpe[s * ROT + r];
    float c = cosf(ang), sn = sinf(ang);
    float t1 = p[r], t2 = p[r + ROT];
    p[r]       = t1 * c - t2 * sn;
    p[r + ROT] = t2 * c + t1 * sn;
}

// ---------------------------------------------------------------------------
// MFMA flash attention — BYTE-IDENTICAL to round 4 (under validation).
// ---------------------------------------------------------------------------
#define KSTR 104
#define VSTR 72
#define PSTR 72

__global__ __launch_bounds__(256) void attn_mfma_kernel(
    const float* __restrict__ Qb, const float* __restrict__ Kb,
    const float* __restrict__ Vb, const int* __restrict__ cu, int nseg,
    float* __restrict__ ctx)
{
    __shared__ unsigned short kv_hi[64 * KSTR];   // K: [key][104] | V: [d][72]
    __shared__ unsigned short kv_lo[64 * KSTR];
    __shared__ unsigned short p_hi[64 * PSTR];
    __shared__ unsigned short p_lo[64 * PSTR];

    const int tid  = threadIdx.x;
    const int lane = tid & 63;
    const int wave = tid >> 6;
    const int lg   = lane >> 4;        // 0..3
    const int col  = lane & 15;
    const int h    = blockIdx.y;
    const int r0   = blockIdx.x * 64;
    const int wrow = wave * 16;

    // --- segment bounds: exact searchsorted(cu[1:], pos, 'right') semantics
    int qstart[4], qend[4];
#pragma unroll
    for (int q = 0; q < 4; ++q) {
        int row = r0 + wrow + lg * 4 + q;
        int sid = 0;
        for (int i = 1; i <= nseg; ++i) sid += (cu[i] <= row);
        qstart[q] = (sid == 0) ? 0 : cu[sid];
        qend[q]   = (sid >= nseg) ? SEQL : cu[sid + 1];
    }
    int blo, bhi;
    {
        int sid = 0;
        for (int i = 1; i <= nseg; ++i) sid += (cu[i] <= r0);
        blo = (sid == 0) ? 0 : cu[sid];
        sid = 0;
        for (int i = 1; i <= nseg; ++i) sid += (cu[i] <= r0 + 63);
        bhi = (sid >= nseg) ? SEQL : cu[sid + 1];
    }

    // --- Q fragments: A-row = col (wave's row wrow+col), k padded to 96
    const float scale = 0.11180339887498949f;   // 1/sqrt(80)
    short8v qh[3], qlo[3];
    {
        const float* Qr = Qb + ((size_t)h * SEQL + r0 + wrow + col) * HD;
#pragma unroll
        for (int kc = 0; kc < 3; ++kc) {
            int d0 = kc * 32 + lg * 8;
            float v[8];
            if (d0 < HD) {
                float4 f0 = *reinterpret_cast<const float4*>(&Qr[d0]);
                float4 f1 = *reinterpret_cast<const float4*>(&Qr[d0 + 4]);
                v[0] = f0.x * scale; v[1] = f0.y * scale; v[2] = f0.z * scale; v[3] = f0.w * scale;
                v[4] = f1.x * scale; v[5] = f1.y * scale; v[6] = f1.z * scale; v[7] = f1.w * scale;
            } else {
#pragma unroll
                for (int j = 0; j < 8; ++j) v[j] = 0.f;
            }
            short8v hh, ll;
#pragma unroll
            for (int j = 0; j < 8; ++j) {
                unsigned short hb = f2bf(v[j]);
                hh[j] = (short)hb;
                ll[j] = (short)f2bf(v[j] - bf2f(hb));
            }
            qh[kc] = hh; qlo[kc] = ll;
        }
    }

    f32x4 oacc[5];
#pragma unroll
    for (int fn = 0; fn < 5; ++fn) oacc[fn] = (f32x4){0.f, 0.f, 0.f, 0.f};
    float mrun[4] = {-1e30f, -1e30f, -1e30f, -1e30f};
    float lrun[4] = {0.f, 0.f, 0.f, 0.f};

    const float* Kh = Kb + (size_t)h * SEQL * HD;
    const float* Vh = Vb + (size_t)h * SEQL * HD;

    for (int kb = (blo & ~63); kb < bhi; kb += 64) {
        __syncthreads();                 // prior PV reads of kv/pbuf done

        // ---- stage K tile hi/lo: [key][KSTR], coalesced reads
        const float* Kt = Kh + (size_t)kb * HD;
#pragma unroll
        for (int l = 0; l < 5; ++l) {
            int idx = tid + l * 256;     // 64 keys x 20 float4
            int ky = idx / 20, fc = idx % 20;
            float4 f = *reinterpret_cast<const float4*>(&Kt[ky * HD + fc * 4]);
            int base = ky * KSTR + fc * 4;
            unsigned short h0 = f2bf(f.x), h1 = f2bf(f.y), h2 = f2bf(f.z), h3 = f2bf(f.w);
            uint2 w;
            w.x = (unsigned)h0 | ((unsigned)h1 << 16); w.y = (unsigned)h2 | ((unsigned)h3 << 16);
            *reinterpret_cast<uint2*>(&kv_hi[base]) = w;
            h0 = f2bf(f.x - bf2f(h0)); h1 = f2bf(f.y - bf2f(h1));
            h2 = f2bf(f.z - bf2f(h2)); h3 = f2bf(f.w - bf2f(h3));
            w.x = (unsigned)h0 | ((unsigned)h1 << 16); w.y = (unsigned)h2 | ((unsigned)h3 << 16);
            *reinterpret_cast<uint2*>(&kv_lo[base]) = w;
        }
        {   // zero-fill dims 80..95 (both planes)
            int ky = tid >> 2, off = (tid & 3) << 2;
            uint2 z; z.x = 0u; z.y = 0u;
            *reinterpret_cast<uint2*>(&kv_hi[ky * KSTR + 80 + off]) = z;
            *reinterpret_cast<uint2*>(&kv_lo[ky * KSTR + 80 + off]) = z;
        }
        __syncthreads();

        // ---- QK^T: S fragments (col=key, row=lg*4+q)
        f32x4 sfr[4];
#pragma unroll
        for (int kt = 0; kt < 4; ++kt) {
            f32x4 s = (f32x4){0.f, 0.f, 0.f, 0.f};
#pragma unroll
            for (int kc = 0; kc < 3; ++kc) {
                int bidx = (kt * 16 + col) * KSTR + kc * 32 + lg * 8;
                short8v kh = *reinterpret_cast<const short8v*>(&kv_hi[bidx]);
                short8v kl = *reinterpret_cast<const short8v*>(&kv_lo[bidx]);
                s = __builtin_amdgcn_mfma_f32_16x16x32_bf16(qh[kc],  kh, s, 0, 0, 0);
                s = __builtin_amdgcn_mfma_f32_16x16x32_bf16(qlo[kc], kh, s, 0, 0, 0);
                s = __builtin_amdgcn_mfma_f32_16x16x32_bf16(qh[kc],  kl, s, 0, 0, 0);
            }
            sfr[kt] = s;
        }
        __syncthreads();                 // all K reads done -> kv free for V

        // ---- issue V global loads early (latency hides under softmax VALU)
        const float* Vt = Vh + (size_t)kb * HD;
        float4 vreg[5];
#pragma unroll
        for (int l = 0; l < 5; ++l) {
            int idx = tid + l * 256;     // d-major: fc = idx/64, ky = idx%64
            int fc = idx >> 6, ky = idx & 63;
            vreg[l] = *reinterpret_cast<const float4*>(&Vt[ky * HD + fc * 4]);
        }

        // ---- online softmax (per q-row; row spread over 16 lanes x 4 kt)
#pragma unroll
        for (int q = 0; q < 4; ++q) {
            float sv[4];
            float mx = -1e30f;
#pragma unroll
            for (int kt = 0; kt < 4; ++kt) {
                int key = kb + kt * 16 + col;
                bool ok = (key >= qstart[q]) && (key < qend[q]);
                sv[kt] = ok ? sfr[kt][q] : -1e30f;
                mx = fmaxf(mx, sv[kt]);
            }
            mx = fmaxf(mx, __shfl_xor(mx, 1));
            mx = fmaxf(mx, __shfl_xor(mx, 2));
            mx = fmaxf(mx, __shfl_xor(mx, 4));
            mx = fmaxf(mx, __shfl_xor(mx, 8));
            float mnew  = fmaxf(mrun[q], mx);
            float alpha = __expf(mrun[q] - mnew);
            float ps = 0.f;
            int prow = (wrow + lg * 4 + q) * PSTR;
#pragma unroll
            for (int kt = 0; kt < 4; ++kt) {
                float p = (sv[kt] > -1e29f) ? __expf(sv[kt] - mnew) : 0.f;
                ps += p;
                unsigned short ph = f2bf(p);
                p_hi[prow + kt * 16 + col] = ph;
                p_lo[prow + kt * 16 + col] = f2bf(p - bf2f(ph));
            }
            ps += __shfl_xor(ps, 1);
            ps += __shfl_xor(ps, 2);
            ps += __shfl_xor(ps, 4);
            ps += __shfl_xor(ps, 8);
            lrun[q] = lrun[q] * alpha + ps;
            mrun[q] = mnew;
#pragma unroll
            for (int fn = 0; fn < 5; ++fn) oacc[fn][q] *= alpha;
        }

        // ---- write V^T to LDS [d][VSTR] (conflict-free: ky fast-varying)
#pragma unroll
        for (int l = 0; l < 5; ++l) {
            int idx = tid + l * 256;
            int fc = idx >> 6, ky = idx & 63;
            float4 f = vreg[l];
            float vv[4] = {f.x, f.y, f.z, f.w};
#pragma unroll
            for (int e = 0; e < 4; ++e) {
                unsigned short hb = f2bf(vv[e]);
                kv_hi[(fc * 4 + e) * VSTR + ky] = hb;
                kv_lo[(fc * 4 + e) * VSTR + ky] = f2bf(vv[e] - bf2f(hb));
            }
        }
        __syncthreads();                 // V + P ready

        // ---- PV: O += P * V   (A=P rows, B=V^T cols=d, k=keys)
#pragma unroll
        for (int kc2 = 0; kc2 < 2; ++kc2) {
            int aidx = (wrow + col) * PSTR + kc2 * 32 + lg * 8;
            short8v pah = *reinterpret_cast<const short8v*>(&p_hi[aidx]);
            short8v pal = *reinterpret_cast<const short8v*>(&p_lo[aidx]);
#pragma unroll
            for (int fn = 0; fn < 5; ++fn) {
                int bidx = (fn * 16 + col) * VSTR + kc2 * 32 + lg * 8;
                short8v vh = *reinterpret_cast<const short8v*>(&kv_hi[bidx]);
                short8v vl = *reinterpret_cast<const short8v*>(&kv_lo[bidx]);
                oacc[fn] = __builtin_amdgcn_mfma_f32_16x16x32_bf16(pah, vh, oacc[fn], 0, 0, 0);
                oacc[fn] = __builtin_amdgcn_mfma_f32_16x16x32_bf16(pal, vh, oacc[fn], 0, 0, 0);
                oacc[fn] = __builtin_amdgcn_mfma_f32_16x16x32_bf16(pah, vl, oacc[fn], 0, 0, 0);
            }
        }
    }

    // ---- epilogue: ctx[row][h*80 + d] = O/l
#pragma unroll
    for (int q = 0; q < 4; ++q) {
        float inv = 1.f / lrun[q];
        float* cp = &ctx[(size_t)(r0 + wrow + lg * 4 + q) * EMBED + h * HD];
#pragma unroll
        for (int fn = 0; fn < 5; ++fn)
            cp[fn * 16 + col] = oacc[fn][q] * inv;
    }
}

// ---------------------------------------------------------------------------
extern "C" void kernel_launch(void* const* d_in, const int* in_sizes, int n_in,
                              void* d_out, int out_size, void* d_ws, size_t ws_size,
                              hipStream_t stream)
{
    const float* x      = (const float*)d_in[0];
    const float* rpe    = (const float*)d_in[1];
    const int*   cu     = (const int*)d_in[2];
    // d_in[3] = max_seqlen (unused)
    const float* qkv_w  = (const float*)d_in[4];
    const float* qkv_b  = (const float*)d_in[5];
    const float* proj_w = (const float*)d_in[6];
    const float* proj_b = (const float*)d_in[7];

    float* ws  = (float*)d_ws;
    float* Q   = ws;                                 // R0: fp32 2.62M
    float* K   = ws + (size_t)QKV_STRIDE;            // R1
    float* V   = ws + (size_t)2 * QKV_STRIDE;        // R2
    float* ctx = ws + (size_t)3 * QKV_STRIDE;        // R3 (10.5MB)

    const int nseg = in_sizes[2] - 1;

    // Hoisted path needs R3 (x planes, later ctx) + R4 (w planes, later ctx
    // planes) + R5 (proj_w planes): 68,157,440 bytes total.
    const bool HOIST = ws_size >= 68157440ULL;

    if (HOIST) {
        unsigned short* xh   = (unsigned short*)(ws + (size_t)3 * QKV_STRIDE);    // R3
        unsigned short* xl   = xh + (size_t)SEQL * EMBED;
        unsigned short* wh   = (unsigned short*)(ws + (size_t)4 * QKV_STRIDE);    // R4
        unsigned short* wl   = wh + (size_t)QKV_N * EMBED;
        unsigned short* ctxh = (unsigned short*)(ws + (size_t)4 * QKV_STRIDE);    // overlays wh/wl
        unsigned short* ctxl = ctxh + (size_t)SEQL * EMBED;
        unsigned short* ph   = (unsigned short*)((char*)d_ws + 61603840);         // R5
        unsigned short* pl   = ph + (size_t)EMBED * EMBED;

        // 0) pre-split operands into bf16 hi/lo planes
        split_bf16_kernel<<<(SEQL * EMBED / 4 + 255) / 256, 256, 0, stream>>>(x, xh, xl, SEQL * EMBED / 4);
        split_bf16_kernel<<<(QKV_N * EMBED / 4 + 255) / 256, 256, 0, stream>>>(qkv_w, wh, wl, QKV_N * EMBED / 4);
        split_bf16_kernel<<<(EMBED * EMBED / 4 + 255) / 256, 256, 0, stream>>>(proj_w, ph, pl, EMBED * EMBED / 4);

        // 1) QKV projection (hoisted staging) -> Q/K/V [head][seq][dim]
        gemm_mfma_pre_kernel<1><<<dim3(QKV_N / 128, SEQL / 128), 256, 0, stream>>>(
            xh, xl, wh, wl, qkv_b, Q, SEQL, QKV_N, EMBED);

        // 2) rotary on Q,K in place
        rotary_kernel<<<(2 * NHEAD * SEQL * ROT) / 256, 256, 0, stream>>>(Q, K, rpe);

        // 3) segmented MFMA flash attention -> ctx (R3; x planes dead)
        attn_mfma_kernel<<<dim3(SEQL / 64, NHEAD), 256, 0, stream>>>(Q, K, V, cu, nseg, ctx);

        // 4) split ctx -> planes (R4; w planes dead), then output projection
        split_bf16_kernel<<<(SEQL * EMBED / 4 + 255) / 256, 256, 0, stream>>>(ctx, ctxh, ctxl, SEQL * EMBED / 4);
        gemm_mfma_pre_kernel<0><<<dim3(EMBED / 128, SEQL / 128), 256, 0, stream>>>(
            ctxh, ctxl, ph, pl, proj_b, (float*)d_out, SEQL, EMBED, EMBED);
    } else {
        // fallback: fully-validated round-3 pipeline with round-4 attention
        gemm_mfma_kernel<1><<<dim3(QKV_N / 128, SEQL / 128), 256, 0, stream>>>(
            x, qkv_w, qkv_b, Q, SEQL, QKV_N, EMBED);
        rotary_kernel<<<(2 * NHEAD * SEQL * ROT) / 256, 256, 0, stream>>>(Q, K, rpe);
        attn_mfma_kernel<<<dim3(SEQL / 64, NHEAD), 256, 0, stream>>>(Q, K, V, cu, nseg, ctx);
        gemm_mfma_kernel<0><<<dim3(EMBED / 128, SEQL / 128), 256, 0, stream>>>(
            ctx, proj_w, proj_b, (float*)d_out, SEQL, EMBED, EMBED);
    }
}